// Round 2
// baseline (325.622 us; speedup 1.0000x reference)
//
#include <hip/hip_runtime.h>

// IrisSpecializedLoss — fused single-pass loss on MI355X (gfx950).
// B=4096; one 256-thread block per batch; each thread owns 4 consecutive
// pixels (900 = 4*225) so ALL streams are aligned float4/int4 loads:
//   logits  [B,C,900] : 10x float4 per thread (stride-900 channel planes)
//   att     [B,900,C] : 10x float4 per thread (40 contiguous floats)
//   targets [B,900]   : 1x int4 per thread
// Per-pixel terms (no neighbor comms needed):
//   ce      : m + log(sum exp(x-m)) - x_t    (x_t via unrolled cndmask — NO
//             runtime register indexing, avoids scratch spill)
//   exact   : argmax==t (strict > keeps first-max, matches JAX)
//   cons    : eq * w(h)*w(w), w=1 at border else 2  (integer-exact)
//   colormap: sum a^2 - 2*a_t + 1 per pixel  (== MSE vs one-hot * C*HW)
//   rules   : 10-bit presence mask -> s-th set bit per slot
// Block partials -> ws -> deterministic double reduce in a tail kernel.

namespace {
constexpr int kB = 4096;
constexpr int kC = 10;
constexpr int kH = 30;
constexpr int kW = 30;
constexpr int kHW = kH * kW;      // 900
constexpr int kCHW = kC * kHW;    // 9000
constexpr int kThreads = 256;
constexpr int kP4 = kHW / 4;      // 225 working threads per block
}  // namespace

__global__ __launch_bounds__(kThreads) void iris_main(
    const float* __restrict__ logits_g,   // [B,C,H,W]
    const int* __restrict__ targets_g,    // [B,H,W]
    const float* __restrict__ att_g,      // [B,H,W,C]
    const float* __restrict__ rules_g,    // [B,C]
    float* __restrict__ ce_part,          // [B]
    float* __restrict__ cm_part,          // [B]
    unsigned* __restrict__ weq_part,      // [B]
    unsigned* __restrict__ eq_part,       // [B]
    float* __restrict__ rule_part)        // [B]
{
    const int b = blockIdx.x;
    const int tid = threadIdx.x;
    const float* __restrict__ logits = logits_g + (size_t)b * kCHW;
    const int* __restrict__ tgt = targets_g + (size_t)b * kHW;
    const float* __restrict__ att = att_g + (size_t)b * (kHW * kC);

    float ce_acc = 0.f, cm_acc = 0.f;
    unsigned weq_acc = 0u, eq_acc = 0u, mask_acc = 0u;

    if (tid < kP4) {
        const int p0 = tid * 4;

        const int4 tv = *reinterpret_cast<const int4*>(tgt + p0);
        const int ta[4] = {tv.x, tv.y, tv.z, tv.w};
        mask_acc = (1u << ta[0]) | (1u << ta[1]) | (1u << ta[2]) | (1u << ta[3]);

        // ---- logits: 10 channel-plane float4 loads -> x[c][j], all
        //      constant-indexed (stays in VGPRs) ----
        float x[kC][4];
#pragma unroll
        for (int c = 0; c < kC; ++c) {
            const float4 v = *reinterpret_cast<const float4*>(logits + c * kHW + p0);
            x[c][0] = v.x; x[c][1] = v.y; x[c][2] = v.z; x[c][3] = v.w;
        }

        float xm[4], xt[4];
        int am[4];
#pragma unroll
        for (int j = 0; j < 4; ++j) { xm[j] = -3.4e38f; xt[j] = 0.f; am[j] = 0; }
#pragma unroll
        for (int c = 0; c < kC; ++c) {
#pragma unroll
            for (int j = 0; j < 4; ++j) {
                const bool gt = x[c][j] > xm[j];       // strict >: first max wins
                am[j] = gt ? c : am[j];
                xm[j] = gt ? x[c][j] : xm[j];
                xt[j] = (c == ta[j]) ? x[c][j] : xt[j]; // compile-time c: cndmask
            }
        }
#pragma unroll
        for (int j = 0; j < 4; ++j) {
            float s = 0.f;
#pragma unroll
            for (int c = 0; c < kC; ++c) s += __expf(x[c][j] - xm[j]);
            ce_acc += xm[j] + __logf(s) - xt[j];

            const unsigned eq = (am[j] == ta[j]) ? 1u : 0u;
            eq_acc += eq;
            const int p = p0 + j;
            const int h = p / kW;
            const int w = p - h * kW;
            const unsigned wgt = ((h == 0 || h == kH - 1) ? 1u : 2u) *
                                 ((w == 0 || w == kW - 1) ? 1u : 2u);
            weq_acc += eq * wgt;
        }

        // ---- attention: 40 contiguous floats = 10 float4;
        //      MSE vs one-hot == sum(a^2) - 2*a_t + 1 per pixel ----
        const float* __restrict__ a = att + (size_t)p0 * kC;
        float at[4] = {0.f, 0.f, 0.f, 0.f};
        float sq = 0.f;
#pragma unroll
        for (int i = 0; i < kC; ++i) {
            const float4 v = *reinterpret_cast<const float4*>(a + i * 4);
            const float av[4] = {v.x, v.y, v.z, v.w};
#pragma unroll
            for (int k = 0; k < 4; ++k) {
                const int e = 4 * i + k;       // 0..39, compile-time
                const int j = e / kC;          // owning pixel
                const int ch = e - j * kC;     // channel
                sq += av[k] * av[k];
                at[j] = (ch == ta[j]) ? av[k] : at[j];
            }
        }
        cm_acc = sq - 2.f * (at[0] + at[1] + at[2] + at[3]) + 4.f;
    }

    // ---- wave reduce (64 lanes) ----
#pragma unroll
    for (int off = 32; off > 0; off >>= 1) {
        ce_acc  += __shfl_down(ce_acc, off);
        cm_acc  += __shfl_down(cm_acc, off);
        weq_acc += __shfl_down(weq_acc, off);
        eq_acc  += __shfl_down(eq_acc, off);
        mask_acc |= __shfl_down(mask_acc, off);
    }

    __shared__ float s_ce[4], s_cm[4];
    __shared__ unsigned s_weq[4], s_eq[4], s_mask[4];
    const int wave = tid >> 6;
    if ((tid & 63) == 0) {
        s_ce[wave] = ce_acc;
        s_cm[wave] = cm_acc;
        s_weq[wave] = weq_acc;
        s_eq[wave] = eq_acc;
        s_mask[wave] = mask_acc;
    }
    __syncthreads();

    if (tid == 0) {
        ce_part[b]  = s_ce[0] + s_ce[1] + s_ce[2] + s_ce[3];
        cm_part[b]  = s_cm[0] + s_cm[1] + s_cm[2] + s_cm[3];
        weq_part[b] = s_weq[0] + s_weq[1] + s_weq[2] + s_weq[3];
        eq_part[b]  = s_eq[0] + s_eq[1] + s_eq[2] + s_eq[3];
        const unsigned mask = s_mask[0] | s_mask[1] | s_mask[2] | s_mask[3];

        // rule target slot s = s-th smallest present color (else 0)
        const float* __restrict__ lr = rules_g + (size_t)b * kC;
        unsigned mrem = mask;
        float rl = 0.f;
#pragma unroll
        for (int s2 = 0; s2 < kC; ++s2) {
            float v = 0.f;
            if (mrem) {
                v = (float)(__ffs(mrem) - 1);
                mrem &= mrem - 1u;
            }
            const float d = lr[s2] - v;
            rl += d * d;
        }
        rule_part[b] = rl;
    }
}

__global__ __launch_bounds__(256) void iris_finalize(
    const float* __restrict__ ce_part,
    const float* __restrict__ cm_part,
    const unsigned* __restrict__ weq_part,
    const unsigned* __restrict__ eq_part,
    const float* __restrict__ rule_part,
    float* __restrict__ out)
{
    const int tid = threadIdx.x;
    double ce = 0.0, cm = 0.0, rl = 0.0;
    unsigned long long weq = 0ull, eqc = 0ull;
    for (int i = tid; i < kB; i += 256) {
        ce += (double)ce_part[i];
        cm += (double)cm_part[i];
        rl += (double)rule_part[i];
        weq += (unsigned long long)weq_part[i];
        eqc += (unsigned long long)eq_part[i];
    }
#pragma unroll
    for (int off = 32; off > 0; off >>= 1) {
        ce  += __shfl_down(ce, off);
        cm  += __shfl_down(cm, off);
        rl  += __shfl_down(rl, off);
        weq += __shfl_down(weq, off);
        eqc += __shfl_down(eqc, off);
    }
    __shared__ double sd[3][4];
    __shared__ unsigned long long su[2][4];
    const int wave = tid >> 6;
    if ((tid & 63) == 0) {
        sd[0][wave] = ce; sd[1][wave] = cm; sd[2][wave] = rl;
        su[0][wave] = weq; su[1][wave] = eqc;
    }
    __syncthreads();
    if (tid == 0) {
        ce  = sd[0][0] + sd[0][1] + sd[0][2] + sd[0][3];
        cm  = sd[1][0] + sd[1][1] + sd[1][2] + sd[1][3];
        rl  = sd[2][0] + sd[2][1] + sd[2][2] + sd[2][3];
        weq = su[0][0] + su[0][1] + su[0][2] + su[0][3];
        eqc = su[1][0] + su[1][1] + su[1][2] + su[1][3];

        const double ce_m = ce / ((double)kB * kHW);
        const double cm_m = cm / ((double)kB * kHW * kC);
        const double s_mean = (double)weq / ((double)kB * (kH - 1) * (kW - 1));
        const double cons = 1.0 - s_mean / 4.0;
        const double rl_m = rl / ((double)kB * kC);
        const double exact = (double)eqc;
        double total = ce_m + 0.4 * cm_m + 0.3 * cons + 0.2 * rl_m
                       - (exact / (double)kB) * 5.0;
        if (total < 0.001) total = 0.001;
        out[0] = (float)total;
        out[1] = (float)ce_m;
        out[2] = (float)cm_m;
        out[3] = (float)cons;
        out[4] = (float)rl_m;
        out[5] = (float)exact;
    }
}

extern "C" void kernel_launch(void* const* d_in, const int* in_sizes, int n_in,
                              void* d_out, int out_size, void* d_ws, size_t ws_size,
                              hipStream_t stream) {
    const float* color_output    = (const float*)d_in[0];
    const int*   targets         = (const int*)d_in[1];
    const float* color_attention = (const float*)d_in[2];
    const float* lstm_rules      = (const float*)d_in[3];
    float* out = (float*)d_out;

    // workspace layout: 5 arrays of kB entries (80 KB total)
    float*    ce_part   = (float*)d_ws;
    float*    cm_part   = ce_part + kB;
    unsigned* weq_part  = (unsigned*)(cm_part + kB);
    unsigned* eq_part   = weq_part + kB;
    float*    rule_part = (float*)(eq_part + kB);

    iris_main<<<kB, kThreads, 0, stream>>>(color_output, targets, color_attention,
                                           lstm_rules, ce_part, cm_part,
                                           weq_part, eq_part, rule_part);
    iris_finalize<<<1, 256, 0, stream>>>(ce_part, cm_part, weq_part, eq_part,
                                         rule_part, out);
}

// Round 5
// 315.928 us; speedup vs baseline: 1.0307x; 1.0307x over previous
//
#include <hip/hip_runtime.h>

// IrisSpecializedLoss — fused single-pass loss on MI355X (gfx950).
// Round-5 = round-3/4 theory (never ran: GPU timeouts), hardened.
// Measured baseline (round-2): 115 µs, VGPR=32, HBM 16.6%, VALUBusy 15%,
// WRITE_SIZE 742KB -> compiler chose tiny-register allocation, sank loads
// into serial use-sites and spilled x[10][4]. Fixes:
//  * __launch_bounds__(256, 4) ONLY (min 4 waves/EU -> 128-VGPR cap; the
//    round-4 extra amdgpu_waves_per_eu attr dropped: one unambiguous knob).
//  * Head load cluster: targets int4 FIRST, then 10 independent logits
//    float4 planes, then the 4 a_t gathers (depend only on targets ->
//    counted-vmcnt wait keeps logits in flight). sched_barrier(0) after the
//    cluster forbids the scheduler from re-sinking loads (the round-2
//    failure mode). One fence only — loads above, compute below.
//  * att MSE decomposed: sum(a-onehot)^2 = sum(a^2) - 2*sum(a_t) + #px.
//    sum(a^2) is a flat lane-contiguous float4 sweep (1024B/wave-instr,
//    each line once); gather latency drains under the sweep.
// Per-pixel terms: ce = m + log(sum exp(x-m)) - x_t (x_t via unrolled
// cndmask — no runtime register indexing); eq integer-exact; consistency =
// border-weighted eq sum; rules from 10-bit presence mask. Block partials
// -> ws -> deterministic double reduce in iris_finalize.

namespace {
constexpr int kB = 4096;
constexpr int kC = 10;
constexpr int kH = 30;
constexpr int kW = 30;
constexpr int kHW = kH * kW;      // 900
constexpr int kCHW = kC * kHW;    // 9000
constexpr int kThreads = 256;
constexpr int kP4 = kHW / 4;      // 225 pixel-quantum threads
constexpr int kF4 = kCHW / 4;     // 2250 float4s of att per batch
}  // namespace

__global__ __launch_bounds__(kThreads, 4) void iris_main(
    const float* __restrict__ logits_g,   // [B,C,H,W]
    const int* __restrict__ targets_g,    // [B,H,W]
    const float* __restrict__ att_g,      // [B,H,W,C]
    const float* __restrict__ rules_g,    // [B,C]
    float* __restrict__ ce_part,          // [B]
    float* __restrict__ cm_part,          // [B] (sum a^2 - 2 sum a_t; +1/px in finalize)
    unsigned* __restrict__ weq_part,      // [B]
    unsigned* __restrict__ eq_part,       // [B]
    float* __restrict__ rule_part)        // [B]
{
    const int b = blockIdx.x;
    const int tid = threadIdx.x;
    const float* __restrict__ logits = logits_g + (size_t)b * kCHW;
    const int* __restrict__ tgt = targets_g + (size_t)b * kHW;
    const float* __restrict__ att = att_g + (size_t)b * kCHW;

    float ce_acc = 0.f, cm_acc = 0.f;
    unsigned weq_acc = 0u, eq_acc = 0u, mask_acc = 0u;

    const bool owner = (tid < kP4);
    const int p0 = tid * 4;

    // ---- HEAD LOAD CLUSTER: issue everything per-pixel up front ----
    int ta[4] = {0, 0, 0, 0};
    float x[kC][4];
    float atg[4] = {0.f, 0.f, 0.f, 0.f};
    if (owner) {
        const int4 tv = *reinterpret_cast<const int4*>(tgt + p0);   // oldest in flight
        ta[0] = tv.x; ta[1] = tv.y; ta[2] = tv.z; ta[3] = tv.w;
#pragma unroll
        for (int c = 0; c < kC; ++c) {                               // 10 independent
            const float4 v = *reinterpret_cast<const float4*>(logits + c * kHW + p0);
            x[c][0] = v.x; x[c][1] = v.y; x[c][2] = v.z; x[c][3] = v.w;
        }
        mask_acc = (1u << ta[0]) | (1u << ta[1]) | (1u << ta[2]) | (1u << ta[3]);
#pragma unroll
        for (int j = 0; j < 4; ++j)                                  // waits on tv only
            atg[j] = att[(p0 + j) * kC + ta[j]];
    }
    __builtin_amdgcn_sched_barrier(0);  // loads stay above; compute below

    // ---- flat att sum-of-squares sweep (all 256 threads, lane-contiguous
    //      float4 = 1024B/wave-instr); head-cluster loads drain underneath ----
    {
        float sq = 0.f;
#pragma unroll
        for (int k = 0; k < 8; ++k) {
            const float4 v = *reinterpret_cast<const float4*>(att + 4 * (tid + kThreads * k));
            sq += v.x * v.x + v.y * v.y + v.z * v.z + v.w * v.w;
        }
        if (tid < kF4 - 8 * kThreads) {  // tail: 202 float4s
            const float4 v = *reinterpret_cast<const float4*>(att + 4 * (tid + kThreads * 8));
            sq += v.x * v.x + v.y * v.y + v.z * v.z + v.w * v.w;
        }
        cm_acc = sq;
    }

    if (owner) {
        cm_acc -= 2.f * (atg[0] + atg[1] + atg[2] + atg[3]);  // +1/px in finalize

        // ---- softmax + argmax over the resident x[10][4] ----
        float xm[4], xt[4];
        int am[4];
#pragma unroll
        for (int j = 0; j < 4; ++j) { xm[j] = -3.4e38f; xt[j] = 0.f; am[j] = 0; }
#pragma unroll
        for (int c = 0; c < kC; ++c) {
#pragma unroll
            for (int j = 0; j < 4; ++j) {
                const bool gt = x[c][j] > xm[j];        // strict >: first max (JAX)
                am[j] = gt ? c : am[j];
                xm[j] = gt ? x[c][j] : xm[j];
                xt[j] = (c == ta[j]) ? x[c][j] : xt[j]; // compile-time c -> cndmask
            }
        }
#pragma unroll
        for (int j = 0; j < 4; ++j) {
            float s = 0.f;
#pragma unroll
            for (int c = 0; c < kC; ++c) s += __expf(x[c][j] - xm[j]);
            ce_acc += xm[j] + __logf(s) - xt[j];

            const unsigned eq = (am[j] == ta[j]) ? 1u : 0u;
            eq_acc += eq;
            const int p = p0 + j;
            const int h = p / kW;
            const int w = p - h * kW;
            const unsigned wgt = ((h == 0 || h == kH - 1) ? 1u : 2u) *
                                 ((w == 0 || w == kW - 1) ? 1u : 2u);
            weq_acc += eq * wgt;
        }
    }

    // ---- wave reduce (64 lanes) ----
#pragma unroll
    for (int off = 32; off > 0; off >>= 1) {
        ce_acc  += __shfl_down(ce_acc, off);
        cm_acc  += __shfl_down(cm_acc, off);
        weq_acc += __shfl_down(weq_acc, off);
        eq_acc  += __shfl_down(eq_acc, off);
        mask_acc |= __shfl_down(mask_acc, off);
    }

    __shared__ float s_ce[4], s_cm[4];
    __shared__ unsigned s_weq[4], s_eq[4], s_mask[4];
    const int wave = tid >> 6;
    if ((tid & 63) == 0) {
        s_ce[wave] = ce_acc;
        s_cm[wave] = cm_acc;
        s_weq[wave] = weq_acc;
        s_eq[wave] = eq_acc;
        s_mask[wave] = mask_acc;
    }
    __syncthreads();

    if (tid == 0) {
        ce_part[b]  = s_ce[0] + s_ce[1] + s_ce[2] + s_ce[3];
        cm_part[b]  = s_cm[0] + s_cm[1] + s_cm[2] + s_cm[3];
        weq_part[b] = s_weq[0] + s_weq[1] + s_weq[2] + s_weq[3];
        eq_part[b]  = s_eq[0] + s_eq[1] + s_eq[2] + s_eq[3];
        const unsigned mask = s_mask[0] | s_mask[1] | s_mask[2] | s_mask[3];

        // rule target slot s = s-th smallest present color (else 0)
        const float* __restrict__ lr = rules_g + (size_t)b * kC;
        unsigned mrem = mask;
        float rl = 0.f;
#pragma unroll
        for (int s2 = 0; s2 < kC; ++s2) {
            float v = 0.f;
            if (mrem) {
                v = (float)(__ffs(mrem) - 1);
                mrem &= mrem - 1u;
            }
            const float d = lr[s2] - v;
            rl += d * d;
        }
        rule_part[b] = rl;
    }
}

__global__ __launch_bounds__(1024) void iris_finalize(
    const float* __restrict__ ce_part,
    const float* __restrict__ cm_part,
    const unsigned* __restrict__ weq_part,
    const unsigned* __restrict__ eq_part,
    const float* __restrict__ rule_part,
    float* __restrict__ out)
{
    const int tid = threadIdx.x;
    double ce = 0.0, cm = 0.0, rl = 0.0;
    unsigned long long weq = 0ull, eqc = 0ull;
#pragma unroll
    for (int k = 0; k < 4; ++k) {
        const int i = tid + 1024 * k;
        ce += (double)ce_part[i];
        cm += (double)cm_part[i];
        rl += (double)rule_part[i];
        weq += (unsigned long long)weq_part[i];
        eqc += (unsigned long long)eq_part[i];
    }
#pragma unroll
    for (int off = 32; off > 0; off >>= 1) {
        ce  += __shfl_down(ce, off);
        cm  += __shfl_down(cm, off);
        rl  += __shfl_down(rl, off);
        weq += __shfl_down(weq, off);
        eqc += __shfl_down(eqc, off);
    }
    __shared__ double sd[3][16];
    __shared__ unsigned long long su[2][16];
    const int wave = tid >> 6;
    if ((tid & 63) == 0) {
        sd[0][wave] = ce; sd[1][wave] = cm; sd[2][wave] = rl;
        su[0][wave] = weq; su[1][wave] = eqc;
    }
    __syncthreads();
    if (tid == 0) {
        ce = 0.0; cm = 0.0; rl = 0.0; weq = 0ull; eqc = 0ull;
#pragma unroll
        for (int i = 0; i < 16; ++i) {
            ce += sd[0][i]; cm += sd[1][i]; rl += sd[2][i];
            weq += su[0][i]; eqc += su[1][i];
        }
        const double ce_m = ce / ((double)kB * kHW);
        // cm_part = sum a^2 - 2 sum a_t; add the +1-per-pixel constant here
        const double cm_m = (cm + (double)kB * kHW) / ((double)kB * kHW * kC);
        const double s_mean = (double)weq / ((double)kB * (kH - 1) * (kW - 1));
        const double cons = 1.0 - s_mean / 4.0;
        const double rl_m = rl / ((double)kB * kC);
        const double exact = (double)eqc;
        double total = ce_m + 0.4 * cm_m + 0.3 * cons + 0.2 * rl_m
                       - (exact / (double)kB) * 5.0;
        if (total < 0.001) total = 0.001;
        out[0] = (float)total;
        out[1] = (float)ce_m;
        out[2] = (float)cm_m;
        out[3] = (float)cons;
        out[4] = (float)rl_m;
        out[5] = (float)exact;
    }
}

extern "C" void kernel_launch(void* const* d_in, const int* in_sizes, int n_in,
                              void* d_out, int out_size, void* d_ws, size_t ws_size,
                              hipStream_t stream) {
    const float* color_output    = (const float*)d_in[0];
    const int*   targets         = (const int*)d_in[1];
    const float* color_attention = (const float*)d_in[2];
    const float* lstm_rules      = (const float*)d_in[3];
    float* out = (float*)d_out;

    // workspace layout: 5 arrays of kB entries (80 KB total)
    float*    ce_part   = (float*)d_ws;
    float*    cm_part   = ce_part + kB;
    unsigned* weq_part  = (unsigned*)(cm_part + kB);
    unsigned* eq_part   = weq_part + kB;
    float*    rule_part = (float*)(eq_part + kB);

    iris_main<<<kB, kThreads, 0, stream>>>(color_output, targets, color_attention,
                                           lstm_rules, ce_part, cm_part,
                                           weq_part, eq_part, rule_part);
    iris_finalize<<<1, 1024, 0, stream>>>(ce_part, cm_part, weq_part, eq_part,
                                          rule_part, out);
}